// Round 8
// baseline (243.033 us; speedup 1.0000x reference)
//
#include <hip/hip_runtime.h>

#define H    112
#define W    112
#define HW   12544
#define CIN  64
#define COUT 128
#define BATCH 8
#define KK   9
#define OFFC 18
#define EPS  1e-5f
#define TP   32      // pixels per deform block
#define KDIM 576     // CIN*KK
#define KHALF 288    // K split in two passes
#define KPAD2 296    // samp row stride (elements): 148 words % 32 = 20 -> 2-way max
#define NB   3136    // deform grid size (HW/TP * BATCH)
#define YPAD 36      // yst row pad: 18 words/row -> quads spread over all banks

typedef unsigned short ushort;
typedef unsigned int uint;
typedef _Float16 half2v __attribute__((ext_vector_type(2)));
typedef _Float16 half8  __attribute__((ext_vector_type(8)));
typedef __attribute__((ext_vector_type(4))) float floatx4;

__device__ __forceinline__ half2v u2h(uint u) {
  union { uint u; half2v h; } c; c.u = u; return c.h;
}
__device__ __forceinline__ uint h2u(half2v h) {
  union { uint u; half2v h; } c; c.h = h; return c.u;
}
__device__ __forceinline__ uint pack_h2(float a, float b) {
  half2v h; h[0] = (_Float16)a; h[1] = (_Float16)b; return h2u(h);
}
__device__ __forceinline__ ushort f2h_bits(float v) {
  union { _Float16 h; ushort u; } c; c.h = (_Float16)v; return c.u;
}
__device__ __forceinline__ float h2f_bits(ushort u) {
  union { ushort u; _Float16 h; } c; c.u = u; return (float)c.h;
}

// ---------------- K0: transpose x [B][CIN][HW] -> xTh [B][HW][CIN] f16 ----------------
__global__ __launch_bounds__(256) void k_transpose_x(
    const float* __restrict__ x, ushort* __restrict__ xTh) {
  __shared__ float tile[64][65];
  int b = blockIdx.y;
  int p0 = blockIdx.x * 64;
  int tid = threadIdx.x;
  int j = tid & 63, cb = tid >> 6;
#pragma unroll
  for (int i = 0; i < 16; ++i) {
    int ci = cb * 16 + i;
    tile[ci][j] = x[((size_t)(b * CIN + ci)) * HW + p0 + j];
  }
  __syncthreads();
  int px = tid >> 2, ciq = tid & 3;
#pragma unroll
  for (int g = 0; g < 4; ++g) {
    int ci = ciq * 16 + g * 4;
    uint lo = pack_h2(tile[ci + 0][px], tile[ci + 1][px]);
    uint hi = pack_h2(tile[ci + 2][px], tile[ci + 3][px]);
    *(uint2*)&xTh[((size_t)b * HW + p0 + px) * 64 + ci] = make_uint2(lo, hi);
  }
}

// ---------------- weight prep (f16) ----------------
__global__ __launch_bounds__(256) void k_prep_w(
    const float* __restrict__ w_off, const float* __restrict__ w_dcn,
    ushort* __restrict__ w_offT, ushort* __restrict__ w_mf) {
  int i = blockIdx.x * 256 + threadIdx.x;
  if (i < 32 * KDIM) {
    int oc = i / KDIM, k = i - oc * KDIM;
    int kk = k >> 6, ci = k & 63;
    float v = (oc < OFFC) ? w_off[(oc * CIN + ci) * KK + kk] : 0.f;
    w_offT[i] = f2h_bits(v);
  } else if (i < 32 * KDIM + COUT * KDIM) {
    int jj = i - 32 * KDIM;
    int co = jj / KDIM, k = jj - co * KDIM;
    int h = k / KHALF, r = k - h * KHALF;
    int kk = r >> 5, cil = r & 31;
    int ci = h * 32 + cil;
    w_mf[jj] = f2h_bits(w_dcn[(co * CIN + ci) * KK + kk]);
  }
}

// ---------------- K1: offset conv as register-resident f16 MFMA ----------------
__global__ __launch_bounds__(256) void k_offset_conv(
    const ushort* __restrict__ xTh, const ushort* __restrict__ w_offT,
    const float* __restrict__ bias, float* __restrict__ out) {
  int b = blockIdx.y;
  int wave = threadIdx.x >> 6, lane = threadIdx.x & 63;
  int row16 = lane & 15, quad = lane >> 4;
  int p = blockIdx.x * 64 + wave * 16 + row16;
  int ho = p / W, wo = p - ho * W;
  const ushort* xb = xTh + (size_t)b * HW * 64;

  half8 Bf[18];
#pragma unroll
  for (int ks = 0; ks < 18; ++ks) {
    int kk = ks >> 1;
    int ci0 = (ks & 1) * 32 + quad * 8;
    int kh = kk / 3, kw = kk - kh * 3;
    int yy = ho + kh - 1, xx = wo + kw - 1;
    bool valid = (yy >= 0) & (yy < H) & (xx >= 0) & (xx < W);
    half8 v = {0, 0, 0, 0, 0, 0, 0, 0};
    if (valid) v = *(const half8*)(xb + ((size_t)(yy * W + xx) << 6) + ci0);
    Bf[ks] = v;
  }
  floatx4 acc0 = {0.f, 0.f, 0.f, 0.f}, acc1 = acc0;
  const ushort* wa0 = w_offT + row16 * KDIM + quad * 8;
  const ushort* wa1 = w_offT + (16 + row16) * KDIM + quad * 8;
#pragma unroll
  for (int ks = 0; ks < 18; ++ks) {
    half8 A0 = *(const half8*)(wa0 + ks * 32);
    half8 A1 = *(const half8*)(wa1 + ks * 32);
    acc0 = __builtin_amdgcn_mfma_f32_16x16x32_f16(A0, Bf[ks], acc0, 0, 0, 0);
    acc1 = __builtin_amdgcn_mfma_f32_16x16x32_f16(A1, Bf[ks], acc1, 0, 0, 0);
  }
  float* ob = out + (size_t)b * OFFC * HW;
#pragma unroll
  for (int reg = 0; reg < 4; ++reg) {
    int oc = quad * 4 + reg;
    ob[(size_t)oc * HW + p] = acc0[reg] + bias[oc];
    int oc1 = 16 + oc;
    if (oc1 < OFFC) ob[(size_t)oc1 * HW + p] = acc1[reg] + bias[oc1];
  }
}

// ---------------- K3: deform conv (K-split f16 MFMA) -> y f16 + per-block BN partials ----------------
struct SMemA { uint4 s_wh[KK][TP]; int4 s_i[KK][TP]; ushort samp[TP][KPAD2]; };
struct SMemB { ushort yst[COUT][YPAD]; float stat_s[COUT]; float stat_q[COUT]; };
union SMemU { SMemA a; SMemB b; };

__global__ __launch_bounds__(256) void k_deform(
    const ushort* __restrict__ xTh, const float* __restrict__ off,
    const ushort* __restrict__ w_mf, ushort* __restrict__ y,
    float* __restrict__ psT) {
  __shared__ SMemU sm;

  int b = blockIdx.y;
  int p0 = blockIdx.x * TP;
  int bid = blockIdx.y * gridDim.x + blockIdx.x;
  int tid = threadIdx.x;
  const ushort* xb = xTh + (size_t)b * HW * 64;

  // ---- Phase A: bilinear metadata (288 tasks) ----
  for (int it = tid; it < KK * TP; it += 256) {
    int kk = it >> 5;
    int px = it & 31;
    int p = p0 + px;
    int ho = p / W, wo = p - ho * W;
    float dy = off[((size_t)b * OFFC + 2 * kk) * HW + p];
    float dx = off[((size_t)b * OFFC + 2 * kk + 1) * HW + p];
    float py = dy + (float)(ho - 1 + kk / 3);
    float pxx = dx + (float)(wo - 1 + kk % 3);
    float y0f = floorf(py), x0f = floorf(pxx);
    float wy1 = py - y0f, wx1 = pxx - x0f;
    int y0 = (int)y0f, x0 = (int)x0f;
    int y1 = y0 + 1, x1 = x0 + 1;
    float vy0 = (y0 >= 0 && y0 < H) ? 1.f : 0.f;
    float vy1 = (y1 >= 0 && y1 < H) ? 1.f : 0.f;
    float vx0 = (x0 >= 0 && x0 < W) ? 1.f : 0.f;
    float vx1 = (x1 >= 0 && x1 < W) ? 1.f : 0.f;
    int cy0 = min(max(y0, 0), H - 1), cy1 = min(max(y1, 0), H - 1);
    int cx0 = min(max(x0, 0), W - 1), cx1 = min(max(x1, 0), W - 1);
    float w00 = (1.f - wy1) * (1.f - wx1) * vy0 * vx0;
    float w01 = (1.f - wy1) * wx1 * vy0 * vx1;
    float w10 = wy1 * (1.f - wx1) * vy1 * vx0;
    float w11 = wy1 * wx1 * vy1 * vx1;
    sm.a.s_wh[kk][px] = make_uint4(pack_h2(w00, w00), pack_h2(w01, w01),
                                   pack_h2(w10, w10), pack_h2(w11, w11));
    sm.a.s_i[kk][px] = make_int4((cy0 * W + cx0) << 6, (cy0 * W + cx1) << 6,
                                 (cy1 * W + cx0) << 6, (cy1 * W + cx1) << 6);
  }
  __syncthreads();

  int wave = tid >> 6, lane = tid & 63;
  int row16 = lane & 15, quad = lane >> 4;
  int koff = quad * 8;
  int co_base = wave * 32;
  const ushort* wa0 = w_mf + (size_t)(co_base + row16) * KDIM + koff;
  const ushort* wa1 = w_mf + (size_t)(co_base + 16 + row16) * KDIM + koff;

  floatx4 acc00 = {0.f, 0.f, 0.f, 0.f}, acc01 = acc00, acc10 = acc00, acc11 = acc00;

  for (int h = 0; h < 2; ++h) {
    // ---- gather half h: 1152 tasks = 32px x 9kk x 4cig (8 ch each, packed f16) ----
#pragma unroll
    for (int r = 0; r < 5; ++r) {
      int it = tid + r * 256;
      if (it < 1152) {
        int px = it / 36;
        int rem = it - px * 36;
        int kk = rem >> 2;
        int cig = rem & 3;
        int cil0 = cig * 8;
        int cio = h * 32 + cil0;
        uint4 wh = sm.a.s_wh[kk][px];
        int4 iv = sm.a.s_i[kk][px];
        half2v w0 = u2h(wh.x), w1 = u2h(wh.y), w2 = u2h(wh.z), w3 = u2h(wh.w);
        uint4 c0 = *(const uint4*)(xb + iv.x + cio);
        uint4 c1 = *(const uint4*)(xb + iv.y + cio);
        uint4 c2 = *(const uint4*)(xb + iv.z + cio);
        uint4 c3 = *(const uint4*)(xb + iv.w + cio);
        uint4 res;
        res.x = h2u(w0 * u2h(c0.x) + w1 * u2h(c1.x) + w2 * u2h(c2.x) + w3 * u2h(c3.x));
        res.y = h2u(w0 * u2h(c0.y) + w1 * u2h(c1.y) + w2 * u2h(c2.y) + w3 * u2h(c3.y));
        res.z = h2u(w0 * u2h(c0.z) + w1 * u2h(c1.z) + w2 * u2h(c2.z) + w3 * u2h(c3.z));
        res.w = h2u(w0 * u2h(c0.w) + w1 * u2h(c1.w) + w2 * u2h(c2.w) + w3 * u2h(c3.w));
        *(uint4*)&sm.a.samp[px][kk * 32 + cil0] = res;
      }
    }
    __syncthreads();

    // ---- MFMA over this K-half: 9 ks steps x 4 MFMA ----
    const ushort* sb0 = &sm.a.samp[row16][koff];
    const ushort* sb1 = &sm.a.samp[16 + row16][koff];
    const ushort* a0 = wa0 + h * KHALF;
    const ushort* a1 = wa1 + h * KHALF;
#pragma unroll
    for (int ks = 0; ks < 9; ++ks) {
      half8 A0 = *(const half8*)(a0 + ks * 32);
      half8 A1 = *(const half8*)(a1 + ks * 32);
      half8 B0 = *(const half8*)(sb0 + ks * 32);
      half8 B1 = *(const half8*)(sb1 + ks * 32);
      acc00 = __builtin_amdgcn_mfma_f32_16x16x32_f16(A0, B0, acc00, 0, 0, 0);
      acc01 = __builtin_amdgcn_mfma_f32_16x16x32_f16(A0, B1, acc01, 0, 0, 0);
      acc10 = __builtin_amdgcn_mfma_f32_16x16x32_f16(A1, B0, acc10, 0, 0, 0);
      acc11 = __builtin_amdgcn_mfma_f32_16x16x32_f16(A1, B1, acc11, 0, 0, 0);
    }
    __syncthreads();   // h=0: samp reuse; h=1: before epilogue overlays SMem
  }

  // ---- epilogue 1: per-wave stats (fp32 accs) + LDS staging of y (f16) ----
#pragma unroll
  for (int reg = 0; reg < 4; ++reg) {
    int cA = co_base + quad * 4 + reg;
    int cB = cA + 16;
    sm.b.yst[cA][row16]      = f2h_bits(acc00[reg]);
    sm.b.yst[cA][16 + row16] = f2h_bits(acc01[reg]);
    sm.b.yst[cB][row16]      = f2h_bits(acc10[reg]);
    sm.b.yst[cB][16 + row16] = f2h_bits(acc11[reg]);
    float s0 = acc00[reg] + acc01[reg];
    float q0 = acc00[reg] * acc00[reg] + acc01[reg] * acc01[reg];
    float s1 = acc10[reg] + acc11[reg];
    float q1 = acc10[reg] * acc10[reg] + acc11[reg] * acc11[reg];
#pragma unroll
    for (int m = 1; m < 16; m <<= 1) {
      s0 += __shfl_xor(s0, m, 64);
      q0 += __shfl_xor(q0, m, 64);
      s1 += __shfl_xor(s1, m, 64);
      q1 += __shfl_xor(q1, m, 64);
    }
    if (row16 == 0) {
      sm.b.stat_s[cA] = s0;
      sm.b.stat_q[cA] = q0;
      sm.b.stat_s[cB] = s1;
      sm.b.stat_q[cB] = q1;
    }
  }
  __syncthreads();

  // ---- epilogue 2: cooperative full-line stores ----
  {
    int co = tid >> 1, seg = tid & 1;
    const ushort* row = &sm.b.yst[co][seg * 16];
    uint2 v0 = *(const uint2*)(row + 0);
    uint2 v1 = *(const uint2*)(row + 4);
    uint2 v2 = *(const uint2*)(row + 8);
    uint2 v3 = *(const uint2*)(row + 12);
    ushort* dst = y + (size_t)b * COUT * HW + (size_t)co * HW + p0 + seg * 16;
    *(uint4*)dst       = make_uint4(v0.x, v0.y, v1.x, v1.y);
    *(uint4*)(dst + 8) = make_uint4(v2.x, v2.y, v3.x, v3.y);
    float sv = (tid < 128) ? sm.b.stat_s[tid] : sm.b.stat_q[tid - 128];
    psT[(size_t)bid * 256 + tid] = sv;
  }
}

// ---------------- K4: reduce per-block partials -> stats[256] ----------------
// psT[bid][256]; block g sums bids g, g+64, ... with lane-coalesced 1KB reads.
__global__ __launch_bounds__(256) void k_reduce(const float* __restrict__ psT,
                                                float* __restrict__ stats) {
  int tid = threadIdx.x;
  float s = 0.f;
  for (int i = blockIdx.x; i < NB; i += gridDim.x)
    s += psT[(size_t)i * 256 + tid];
  atomicAdd(&stats[tid], s);
}

// ---------------- K5: finalize stats + normalize + ReLU (y f16 -> out fp32) ----------------
__global__ __launch_bounds__(256) void k_norm(const ushort* __restrict__ y,
                                              const float* __restrict__ stats,
                                              const float* __restrict__ gamma,
                                              const float* __restrict__ beta,
                                              float* __restrict__ out) {
  int i8 = blockIdx.x * 256 + threadIdx.x;
  const int total8 = BATCH * COUT * HW / 8;
  if (i8 >= total8) return;
  size_t i = (size_t)i8 * 8;
  int c = (int)((i / HW) & (COUT - 1));
  const float N = (float)(BATCH * HW);
  float m = stats[c] / N;
  float var = stats[COUT + c] / N - m * m;
  float r = rsqrtf(var + EPS);
  float g = gamma[c], bt = beta[c];
  float a = r * g;          // out = (v - m)*a + bt
  float base = bt - m * a;
  uint4 u = *(const uint4*)&y[i];
  float4 o0, o1;
  half2v h0 = u2h(u.x), h1 = u2h(u.y), h2 = u2h(u.z), h3 = u2h(u.w);
  o0.x = fmaxf(0.f, fmaf((float)h0[0], a, base));
  o0.y = fmaxf(0.f, fmaf((float)h0[1], a, base));
  o0.z = fmaxf(0.f, fmaf((float)h1[0], a, base));
  o0.w = fmaxf(0.f, fmaf((float)h1[1], a, base));
  o1.x = fmaxf(0.f, fmaf((float)h2[0], a, base));
  o1.y = fmaxf(0.f, fmaf((float)h2[1], a, base));
  o1.z = fmaxf(0.f, fmaf((float)h3[0], a, base));
  o1.w = fmaxf(0.f, fmaf((float)h3[1], a, base));
  *(float4*)&out[i]     = o0;
  *(float4*)&out[i + 4] = o1;
}

extern "C" void kernel_launch(void* const* d_in, const int* in_sizes, int n_in,
                              void* d_out, int out_size, void* d_ws, size_t ws_size,
                              hipStream_t stream) {
  const float* x     = (const float*)d_in[0];
  const float* w_off = (const float*)d_in[1];
  const float* b_off = (const float*)d_in[2];
  const float* w_dcn = (const float*)d_in[3];
  // d_in[4] = b_dcn: cancels exactly through batch-norm
  const float* gamma = (const float*)d_in[5];
  const float* beta  = (const float*)d_in[6];
  float* out = (float*)d_out;

  float* ws = (float*)d_ws;
  float*  off_buf = ws;                               //  1,806,336 floats
  float*  psT     = off_buf + 1806336;                //    802,816 floats
  float*  stats   = psT + 802816;                     //        256
  ushort* xTh     = (ushort*)(stats + 256);           //  6,422,528 ushorts
  ushort* w_mf    = xTh + 6422528;                    //     73,728
  ushort* w_offT  = w_mf + 73728;                     //     18,432
  ushort* y_h     = w_offT + 18432;                   // 12,845,056 ushorts
  // total ~49 MB

  hipMemsetAsync(stats, 0, 256 * sizeof(float), stream);
  k_transpose_x<<<dim3(HW / 64, BATCH), 256, 0, stream>>>(x, xTh);
  k_prep_w<<<(32 * KDIM + COUT * KDIM + 255) / 256, 256, 0, stream>>>(w_off, w_dcn, w_offT, w_mf);
  k_offset_conv<<<dim3(HW / 64, BATCH), 256, 0, stream>>>(xTh, w_offT, b_off, off_buf);
  k_deform<<<dim3(HW / TP, BATCH), 256, 0, stream>>>(xTh, off_buf, w_mf, y_h, psT);
  k_reduce<<<64, 256, 0, stream>>>(psT, stats);
  k_norm<<<(BATCH * COUT * HW / 8 + 255) / 256, 256, 0, stream>>>(y_h, stats, gamma, beta, out);
}

// Round 9
// 237.112 us; speedup vs baseline: 1.0250x; 1.0250x over previous
//
#include <hip/hip_runtime.h>

#define H    112
#define W    112
#define HW   12544
#define CIN  64
#define COUT 128
#define BATCH 8
#define KK   9
#define OFFC 18
#define EPS  1e-5f
#define TP   32      // pixels per deform block
#define KDIM 576     // CIN*KK
#define KHALF 288    // K split in two passes
#define KPAD2 296    // samp row stride (elements): 148 words % 32 = 20 -> 2-way max
#define NB   3136    // deform grid size (HW/TP * BATCH)
#define YPAD 36      // yst row pad

typedef unsigned short ushort;
typedef unsigned int uint;
typedef _Float16 half2v __attribute__((ext_vector_type(2)));
typedef _Float16 half8  __attribute__((ext_vector_type(8)));
typedef __attribute__((ext_vector_type(4))) float floatx4;

__device__ __forceinline__ half2v u2h(uint u) {
  union { uint u; half2v h; } c; c.u = u; return c.h;
}
__device__ __forceinline__ uint h2u(half2v h) {
  union { uint u; half2v h; } c; c.h = h; return c.u;
}
__device__ __forceinline__ uint pack_h2(float a, float b) {
  half2v h; h[0] = (_Float16)a; h[1] = (_Float16)b; return h2u(h);
}
__device__ __forceinline__ ushort f2h_bits(float v) {
  union { _Float16 h; ushort u; } c; c.h = (_Float16)v; return c.u;
}

// ---------------- K0: fused transpose (x -> xTh f16) + weight prep ----------------
// 1D grid: blocks [0,1568) transpose; [1568,1928) prep weights.
__global__ __launch_bounds__(256) void k_transpose_prep(
    const float* __restrict__ x, const float* __restrict__ w_off,
    const float* __restrict__ w_dcn, ushort* __restrict__ xTh,
    ushort* __restrict__ w_offT, ushort* __restrict__ w_mf) {
  __shared__ float tile[64][65];
  int tb = blockIdx.x;
  int tid = threadIdx.x;
  if (tb < 1568) {
    int b = tb / 196;
    int p0 = (tb - b * 196) * 64;
    int j = tid & 63, cb = tid >> 6;
#pragma unroll
    for (int i = 0; i < 16; ++i) {
      int ci = cb * 16 + i;
      tile[ci][j] = x[((size_t)(b * CIN + ci)) * HW + p0 + j];
    }
    __syncthreads();
    int px = tid >> 2, ciq = tid & 3;
#pragma unroll
    for (int g = 0; g < 4; ++g) {
      int ci = ciq * 16 + g * 4;
      uint lo = pack_h2(tile[ci + 0][px], tile[ci + 1][px]);
      uint hi = pack_h2(tile[ci + 2][px], tile[ci + 3][px]);
      *(uint2*)&xTh[((size_t)b * HW + p0 + px) * 64 + ci] = make_uint2(lo, hi);
    }
  } else {
    int i = (tb - 1568) * 256 + tid;
    if (i < 32 * KDIM) {
      // w_offT[oc][kk*64+ci], oc padded to 32 with zeros
      int oc = i / KDIM, k = i - oc * KDIM;
      int kk = k >> 6, ci = k & 63;
      float v = (oc < OFFC) ? w_off[(oc * CIN + ci) * KK + kk] : 0.f;
      w_offT[i] = f2h_bits(v);
    } else if (i < 32 * KDIM + COUT * KDIM) {
      // w_mf[co][h*288 + kk*32 + cil], ci = h*32+cil
      int jj = i - 32 * KDIM;
      int co = jj / KDIM, k = jj - co * KDIM;
      int h = k / KHALF, r = k - h * KHALF;
      int kk = r >> 5, cil = r & 31;
      int ci = h * 32 + cil;
      w_mf[jj] = f2h_bits(w_dcn[(co * CIN + ci) * KK + kk]);
    }
  }
}

// ---------------- K3: fully fused deform block ----------------
// Phase 0: offset conv for this block's 32 px via register MFMA -> off_s (LDS)
// Phase A: bilinear metadata; Phase B/C: K-split gather + MFMA; epilogue:
// LDS-staged full-line f16 y stores + coalesced per-block BN partials.
struct SMemA { uint4 s_wh[KK][TP]; int4 s_i[KK][TP]; ushort samp[TP][KPAD2]; };
struct SMemB { ushort yst[COUT][YPAD]; float stat_s[COUT]; float stat_q[COUT]; };
union SMemU { SMemA a; SMemB b; };

__global__ __launch_bounds__(256) void k_deform(
    const ushort* __restrict__ xTh, const ushort* __restrict__ w_offT,
    const float* __restrict__ b_off, const ushort* __restrict__ w_mf,
    ushort* __restrict__ y, float* __restrict__ psT) {
  __shared__ SMemU sm;
  __shared__ float off_s[OFFC][33];

  int b = blockIdx.y;
  int p0 = blockIdx.x * TP;
  int bid = blockIdx.y * gridDim.x + blockIdx.x;
  int tid = threadIdx.x;
  const ushort* xb = xTh + (size_t)b * HW * 64;

  int wave = tid >> 6, lane = tid & 63;
  int row16 = lane & 15, quad = lane >> 4;

  // ---- Phase 0: offset conv. wave -> (pxh = wave>>1, mt = wave&1) ----
  {
    int pxh = wave >> 1, mt = wave & 1;
    int p = p0 + pxh * 16 + row16;
    int ho = p / W, wo = p - ho * W;
    floatx4 oacc = {0.f, 0.f, 0.f, 0.f};
    const ushort* wa = w_offT + (size_t)(mt * 16 + row16) * KDIM + quad * 8;
    half8 Bf[9];
#pragma unroll
    for (int c = 0; c < 2; ++c) {
#pragma unroll
      for (int j = 0; j < 9; ++j) {
        int ks = c * 9 + j;
        int kk = ks >> 1;
        int ci0 = (ks & 1) * 32 + quad * 8;
        int kh = kk / 3, kw = kk - kh * 3;
        int yy = ho + kh - 1, xx = wo + kw - 1;
        bool valid = (yy >= 0) & (yy < H) & (xx >= 0) & (xx < W);
        half8 v = {0, 0, 0, 0, 0, 0, 0, 0};
        if (valid) v = *(const half8*)(xb + ((size_t)(yy * W + xx) << 6) + ci0);
        Bf[j] = v;
      }
#pragma unroll
      for (int j = 0; j < 9; ++j) {
        int ks = c * 9 + j;
        half8 A = *(const half8*)(wa + ks * 32);
        oacc = __builtin_amdgcn_mfma_f32_16x16x32_f16(A, Bf[j], oacc, 0, 0, 0);
      }
    }
    // C/D: col = lane&15 (px within this wave's 16-px half), row = quad*4+reg
#pragma unroll
    for (int reg = 0; reg < 4; ++reg) {
      int oc = mt * 16 + quad * 4 + reg;
      if (oc < OFFC)
        off_s[oc][pxh * 16 + row16] = oacc[reg] + b_off[oc];
    }
  }
  __syncthreads();

  // ---- Phase A: bilinear metadata (288 tasks) ----
  for (int it = tid; it < KK * TP; it += 256) {
    int kk = it >> 5;
    int px = it & 31;
    int p = p0 + px;
    int ho = p / W, wo = p - ho * W;
    float dy = off_s[2 * kk][px];
    float dx = off_s[2 * kk + 1][px];
    float py = dy + (float)(ho - 1 + kk / 3);
    float pxx = dx + (float)(wo - 1 + kk % 3);
    float y0f = floorf(py), x0f = floorf(pxx);
    float wy1 = py - y0f, wx1 = pxx - x0f;
    int y0 = (int)y0f, x0 = (int)x0f;
    int y1 = y0 + 1, x1 = x0 + 1;
    float vy0 = (y0 >= 0 && y0 < H) ? 1.f : 0.f;
    float vy1 = (y1 >= 0 && y1 < H) ? 1.f : 0.f;
    float vx0 = (x0 >= 0 && x0 < W) ? 1.f : 0.f;
    float vx1 = (x1 >= 0 && x1 < W) ? 1.f : 0.f;
    int cy0 = min(max(y0, 0), H - 1), cy1 = min(max(y1, 0), H - 1);
    int cx0 = min(max(x0, 0), W - 1), cx1 = min(max(x1, 0), W - 1);
    float w00 = (1.f - wy1) * (1.f - wx1) * vy0 * vx0;
    float w01 = (1.f - wy1) * wx1 * vy0 * vx1;
    float w10 = wy1 * (1.f - wx1) * vy1 * vx0;
    float w11 = wy1 * wx1 * vy1 * vx1;
    sm.a.s_wh[kk][px] = make_uint4(pack_h2(w00, w00), pack_h2(w01, w01),
                                   pack_h2(w10, w10), pack_h2(w11, w11));
    sm.a.s_i[kk][px] = make_int4((cy0 * W + cx0) << 6, (cy0 * W + cx1) << 6,
                                 (cy1 * W + cx0) << 6, (cy1 * W + cx1) << 6);
  }
  __syncthreads();

  int koff = quad * 8;
  int co_base = wave * 32;
  const ushort* wa0 = w_mf + (size_t)(co_base + row16) * KDIM + koff;
  const ushort* wa1 = w_mf + (size_t)(co_base + 16 + row16) * KDIM + koff;

  floatx4 acc00 = {0.f, 0.f, 0.f, 0.f}, acc01 = acc00, acc10 = acc00, acc11 = acc00;

  for (int h = 0; h < 2; ++h) {
    // ---- gather half h: 1152 tasks = 32px x 9kk x 4cig (8 ch each, packed f16) ----
#pragma unroll
    for (int r = 0; r < 5; ++r) {
      int it = tid + r * 256;
      if (it < 1152) {
        int px = it / 36;
        int rem = it - px * 36;
        int kk = rem >> 2;
        int cig = rem & 3;
        int cil0 = cig * 8;
        int cio = h * 32 + cil0;
        uint4 wh = sm.a.s_wh[kk][px];
        int4 iv = sm.a.s_i[kk][px];
        half2v w0 = u2h(wh.x), w1 = u2h(wh.y), w2 = u2h(wh.z), w3 = u2h(wh.w);
        uint4 c0 = *(const uint4*)(xb + iv.x + cio);
        uint4 c1 = *(const uint4*)(xb + iv.y + cio);
        uint4 c2 = *(const uint4*)(xb + iv.z + cio);
        uint4 c3 = *(const uint4*)(xb + iv.w + cio);
        uint4 res;
        res.x = h2u(w0 * u2h(c0.x) + w1 * u2h(c1.x) + w2 * u2h(c2.x) + w3 * u2h(c3.x));
        res.y = h2u(w0 * u2h(c0.y) + w1 * u2h(c1.y) + w2 * u2h(c2.y) + w3 * u2h(c3.y));
        res.z = h2u(w0 * u2h(c0.z) + w1 * u2h(c1.z) + w2 * u2h(c2.z) + w3 * u2h(c3.z));
        res.w = h2u(w0 * u2h(c0.w) + w1 * u2h(c1.w) + w2 * u2h(c2.w) + w3 * u2h(c3.w));
        *(uint4*)&sm.a.samp[px][kk * 32 + cil0] = res;
      }
    }
    __syncthreads();

    // ---- MFMA over this K-half: 9 ks steps x 4 MFMA ----
    const ushort* sb0 = &sm.a.samp[row16][koff];
    const ushort* sb1 = &sm.a.samp[16 + row16][koff];
    const ushort* a0 = wa0 + h * KHALF;
    const ushort* a1 = wa1 + h * KHALF;
#pragma unroll
    for (int ks = 0; ks < 9; ++ks) {
      half8 A0 = *(const half8*)(a0 + ks * 32);
      half8 A1 = *(const half8*)(a1 + ks * 32);
      half8 B0 = *(const half8*)(sb0 + ks * 32);
      half8 B1 = *(const half8*)(sb1 + ks * 32);
      acc00 = __builtin_amdgcn_mfma_f32_16x16x32_f16(A0, B0, acc00, 0, 0, 0);
      acc01 = __builtin_amdgcn_mfma_f32_16x16x32_f16(A0, B1, acc01, 0, 0, 0);
      acc10 = __builtin_amdgcn_mfma_f32_16x16x32_f16(A1, B0, acc10, 0, 0, 0);
      acc11 = __builtin_amdgcn_mfma_f32_16x16x32_f16(A1, B1, acc11, 0, 0, 0);
    }
    __syncthreads();   // h=0: samp reuse; h=1: before epilogue overlays SMem
  }

  // ---- epilogue 1: per-wave stats (fp32 accs) + LDS staging of y (f16) ----
#pragma unroll
  for (int reg = 0; reg < 4; ++reg) {
    int cA = co_base + quad * 4 + reg;
    int cB = cA + 16;
    sm.b.yst[cA][row16]      = f2h_bits(acc00[reg]);
    sm.b.yst[cA][16 + row16] = f2h_bits(acc01[reg]);
    sm.b.yst[cB][row16]      = f2h_bits(acc10[reg]);
    sm.b.yst[cB][16 + row16] = f2h_bits(acc11[reg]);
    float s0 = acc00[reg] + acc01[reg];
    float q0 = acc00[reg] * acc00[reg] + acc01[reg] * acc01[reg];
    float s1 = acc10[reg] + acc11[reg];
    float q1 = acc10[reg] * acc10[reg] + acc11[reg] * acc11[reg];
#pragma unroll
    for (int m = 1; m < 16; m <<= 1) {
      s0 += __shfl_xor(s0, m, 64);
      q0 += __shfl_xor(q0, m, 64);
      s1 += __shfl_xor(s1, m, 64);
      q1 += __shfl_xor(q1, m, 64);
    }
    if (row16 == 0) {
      sm.b.stat_s[cA] = s0;
      sm.b.stat_q[cA] = q0;
      sm.b.stat_s[cB] = s1;
      sm.b.stat_q[cB] = q1;
    }
  }
  __syncthreads();

  // ---- epilogue 2: cooperative full-line stores ----
  {
    int co = tid >> 1, seg = tid & 1;
    const ushort* row = &sm.b.yst[co][seg * 16];
    uint2 v0 = *(const uint2*)(row + 0);
    uint2 v1 = *(const uint2*)(row + 4);
    uint2 v2 = *(const uint2*)(row + 8);
    uint2 v3 = *(const uint2*)(row + 12);
    ushort* dst = y + (size_t)b * COUT * HW + (size_t)co * HW + p0 + seg * 16;
    *(uint4*)dst       = make_uint4(v0.x, v0.y, v1.x, v1.y);
    *(uint4*)(dst + 8) = make_uint4(v2.x, v2.y, v3.x, v3.y);
    float sv = (tid < 128) ? sm.b.stat_s[tid] : sm.b.stat_q[tid - 128];
    psT[(size_t)bid * 256 + tid] = sv;
  }
}

// ---------------- K4: reduce per-block partials -> stats[256], no atomics ----------------
// Block g sums stat channels 4g..4g+3 over all NB blocks (float4 strided reads).
__global__ __launch_bounds__(256) void k_reduce(const float* __restrict__ psT,
                                                float* __restrict__ stats) {
  int g = blockIdx.x;       // 0..63
  int tid = threadIdx.x;
  float4 a = make_float4(0.f, 0.f, 0.f, 0.f);
  for (int i = tid; i < NB; i += 256) {
    float4 v = *(const float4*)&psT[(size_t)i * 256 + g * 4];
    a.x += v.x; a.y += v.y; a.z += v.z; a.w += v.w;
  }
#pragma unroll
  for (int o = 32; o > 0; o >>= 1) {
    a.x += __shfl_down(a.x, o, 64);
    a.y += __shfl_down(a.y, o, 64);
    a.z += __shfl_down(a.z, o, 64);
    a.w += __shfl_down(a.w, o, 64);
  }
  __shared__ float4 ls[4];
  int lane = tid & 63, wid = tid >> 6;
  if (lane == 0) ls[wid] = a;
  __syncthreads();
  if (tid == 0) {
    float4 s;
    s.x = ls[0].x + ls[1].x + ls[2].x + ls[3].x;
    s.y = ls[0].y + ls[1].y + ls[2].y + ls[3].y;
    s.z = ls[0].z + ls[1].z + ls[2].z + ls[3].z;
    s.w = ls[0].w + ls[1].w + ls[2].w + ls[3].w;
    *(float4*)&stats[g * 4] = s;
  }
}

// ---------------- K5: finalize stats + normalize + ReLU (y f16 -> out fp32) ----------------
__global__ __launch_bounds__(256) void k_norm(const ushort* __restrict__ y,
                                              const float* __restrict__ stats,
                                              const float* __restrict__ gamma,
                                              const float* __restrict__ beta,
                                              float* __restrict__ out) {
  int i8 = blockIdx.x * 256 + threadIdx.x;
  const int total8 = BATCH * COUT * HW / 8;
  if (i8 >= total8) return;
  size_t i = (size_t)i8 * 8;
  int c = (int)((i / HW) & (COUT - 1));
  const float N = (float)(BATCH * HW);
  float m = stats[c] / N;
  float var = stats[COUT + c] / N - m * m;
  float r = rsqrtf(var + EPS);
  float g = gamma[c], bt = beta[c];
  float a = r * g;
  float base = bt - m * a;
  uint4 u = *(const uint4*)&y[i];
  float4 o0, o1;
  half2v h0 = u2h(u.x), h1 = u2h(u.y), h2 = u2h(u.z), h3 = u2h(u.w);
  o0.x = fmaxf(0.f, fmaf((float)h0[0], a, base));
  o0.y = fmaxf(0.f, fmaf((float)h0[1], a, base));
  o0.z = fmaxf(0.f, fmaf((float)h1[0], a, base));
  o0.w = fmaxf(0.f, fmaf((float)h1[1], a, base));
  o1.x = fmaxf(0.f, fmaf((float)h2[0], a, base));
  o1.y = fmaxf(0.f, fmaf((float)h2[1], a, base));
  o1.z = fmaxf(0.f, fmaf((float)h3[0], a, base));
  o1.w = fmaxf(0.f, fmaf((float)h3[1], a, base));
  *(float4*)&out[i]     = o0;
  *(float4*)&out[i + 4] = o1;
}

extern "C" void kernel_launch(void* const* d_in, const int* in_sizes, int n_in,
                              void* d_out, int out_size, void* d_ws, size_t ws_size,
                              hipStream_t stream) {
  const float* x     = (const float*)d_in[0];
  const float* w_off = (const float*)d_in[1];
  const float* b_off = (const float*)d_in[2];
  const float* w_dcn = (const float*)d_in[3];
  // d_in[4] = b_dcn: cancels exactly through batch-norm
  const float* gamma = (const float*)d_in[5];
  const float* beta  = (const float*)d_in[6];
  float* out = (float*)d_out;

  float* ws = (float*)d_ws;
  float*  psT     = ws;                               //    802,816 floats
  float*  stats   = psT + 802816;                     //        256
  ushort* xTh     = (ushort*)(stats + 256);           //  6,422,528 ushorts
  ushort* w_mf    = xTh + 6422528;                    //     73,728
  ushort* w_offT  = w_mf + 73728;                     //     18,432
  ushort* y_h     = w_offT + 18432;                   // 12,845,056 ushorts
  // total ~42 MB

  k_transpose_prep<<<1928, 256, 0, stream>>>(x, w_off, w_dcn, xTh, w_offT, w_mf);
  k_deform<<<dim3(HW / TP, BATCH), 256, 0, stream>>>(xTh, w_offT, b_off, w_mf, y_h, psT);
  k_reduce<<<64, 256, 0, stream>>>(psT, stats);
  k_norm<<<(BATCH * COUT * HW / 8 + 255) / 256, 256, 0, stream>>>(y_h, stats, gamma, beta, out);
}

// Round 10
// 234.243 us; speedup vs baseline: 1.0375x; 1.0122x over previous
//
#include <hip/hip_runtime.h>

#define H    112
#define W    112
#define HW   12544
#define CIN  64
#define COUT 128
#define BATCH 8
#define KK   9
#define OFFC 18
#define EPS  1e-5f
#define TP   32      // pixels per deform block
#define KDIM 576     // CIN*KK
#define KHALF 288    // K split in two passes
#define KPAD2 296    // samp row stride (elements): 148 words % 32 = 20 -> 2-way max
#define NB   3136    // deform grid size (HW/TP * BATCH)
#define YPAD 36      // yst row pad

typedef unsigned short ushort;
typedef unsigned int uint;
typedef _Float16 half2v __attribute__((ext_vector_type(2)));
typedef _Float16 half8  __attribute__((ext_vector_type(8)));
typedef __attribute__((ext_vector_type(4))) float floatx4;

__device__ __forceinline__ half2v u2h(uint u) {
  union { uint u; half2v h; } c; c.u = u; return c.h;
}
__device__ __forceinline__ uint h2u(half2v h) {
  union { uint u; half2v h; } c; c.h = h; return c.u;
}
__device__ __forceinline__ uint pack_h2(float a, float b) {
  half2v h; h[0] = (_Float16)a; h[1] = (_Float16)b; return h2u(h);
}
__device__ __forceinline__ ushort f2h_bits(float v) {
  union { _Float16 h; ushort u; } c; c.h = (_Float16)v; return c.u;
}

// ---------------- K0: fused transpose (x -> xTh f16) + weight prep ----------------
// 1D grid: blocks [0,1568) transpose; [1568,1928) prep weights.
__global__ __launch_bounds__(256) void k_transpose_prep(
    const float* __restrict__ x, const float* __restrict__ w_off,
    const float* __restrict__ w_dcn, ushort* __restrict__ xTh,
    ushort* __restrict__ w_offT, ushort* __restrict__ w_mf) {
  __shared__ float tile[64][65];
  int tb = blockIdx.x;
  int tid = threadIdx.x;
  if (tb < 1568) {
    int b = tb / 196;
    int p0 = (tb - b * 196) * 64;
    int j = tid & 63, cb = tid >> 6;
#pragma unroll
    for (int i = 0; i < 16; ++i) {
      int ci = cb * 16 + i;
      tile[ci][j] = x[((size_t)(b * CIN + ci)) * HW + p0 + j];
    }
    __syncthreads();
    int px = tid >> 2, ciq = tid & 3;
#pragma unroll
    for (int g = 0; g < 4; ++g) {
      int ci = ciq * 16 + g * 4;
      uint lo = pack_h2(tile[ci + 0][px], tile[ci + 1][px]);
      uint hi = pack_h2(tile[ci + 2][px], tile[ci + 3][px]);
      *(uint2*)&xTh[((size_t)b * HW + p0 + px) * 64 + ci] = make_uint2(lo, hi);
    }
  } else {
    int i = (tb - 1568) * 256 + tid;
    if (i < 32 * KDIM) {
      // w_offT[oc][kk*64+ci], oc padded to 32 with zeros
      int oc = i / KDIM, k = i - oc * KDIM;
      int kk = k >> 6, ci = k & 63;
      float v = (oc < OFFC) ? w_off[(oc * CIN + ci) * KK + kk] : 0.f;
      w_offT[i] = f2h_bits(v);
    } else if (i < 32 * KDIM + COUT * KDIM) {
      // w_mf[co][h*288 + kk*32 + cil], ci = h*32+cil
      int jj = i - 32 * KDIM;
      int co = jj / KDIM, k = jj - co * KDIM;
      int h = k / KHALF, r = k - h * KHALF;
      int kk = r >> 5, cil = r & 31;
      int ci = h * 32 + cil;
      w_mf[jj] = f2h_bits(w_dcn[(co * CIN + ci) * KK + kk]);
    }
  }
}

// ---------------- K1: offset conv as register-resident f16 MFMA (standalone) ----------------
// Separate kernel: its 18 scattered loads/wave overlap across 1568 independent
// blocks. (R9 measured: fusing this into k_deform serializes it per-block, +50us.)
__global__ __launch_bounds__(256) void k_offset_conv(
    const ushort* __restrict__ xTh, const ushort* __restrict__ w_offT,
    const float* __restrict__ bias, float* __restrict__ out) {
  int b = blockIdx.y;
  int wave = threadIdx.x >> 6, lane = threadIdx.x & 63;
  int row16 = lane & 15, quad = lane >> 4;
  int p = blockIdx.x * 64 + wave * 16 + row16;
  int ho = p / W, wo = p - ho * W;
  const ushort* xb = xTh + (size_t)b * HW * 64;

  half8 Bf[18];
#pragma unroll
  for (int ks = 0; ks < 18; ++ks) {
    int kk = ks >> 1;
    int ci0 = (ks & 1) * 32 + quad * 8;
    int kh = kk / 3, kw = kk - kh * 3;
    int yy = ho + kh - 1, xx = wo + kw - 1;
    bool valid = (yy >= 0) & (yy < H) & (xx >= 0) & (xx < W);
    half8 v = {0, 0, 0, 0, 0, 0, 0, 0};
    if (valid) v = *(const half8*)(xb + ((size_t)(yy * W + xx) << 6) + ci0);
    Bf[ks] = v;
  }
  floatx4 acc0 = {0.f, 0.f, 0.f, 0.f}, acc1 = acc0;
  const ushort* wa0 = w_offT + row16 * KDIM + quad * 8;
  const ushort* wa1 = w_offT + (16 + row16) * KDIM + quad * 8;
#pragma unroll
  for (int ks = 0; ks < 18; ++ks) {
    half8 A0 = *(const half8*)(wa0 + ks * 32);
    half8 A1 = *(const half8*)(wa1 + ks * 32);
    acc0 = __builtin_amdgcn_mfma_f32_16x16x32_f16(A0, Bf[ks], acc0, 0, 0, 0);
    acc1 = __builtin_amdgcn_mfma_f32_16x16x32_f16(A1, Bf[ks], acc1, 0, 0, 0);
  }
  float* ob = out + (size_t)b * OFFC * HW;
#pragma unroll
  for (int reg = 0; reg < 4; ++reg) {
    int oc = quad * 4 + reg;
    ob[(size_t)oc * HW + p] = acc0[reg] + bias[oc];
    int oc1 = 16 + oc;
    if (oc1 < OFFC) ob[(size_t)oc1 * HW + p] = acc1[reg] + bias[oc1];
  }
}

// ---------------- K3: deform conv (K-split f16 MFMA) -> y f16 + per-block BN partials ----------------
struct SMemA { uint4 s_wh[KK][TP]; int4 s_i[KK][TP]; ushort samp[TP][KPAD2]; };
struct SMemB { ushort yst[COUT][YPAD]; float stat_s[COUT]; float stat_q[COUT]; };
union SMemU { SMemA a; SMemB b; };

__global__ __launch_bounds__(256) void k_deform(
    const ushort* __restrict__ xTh, const float* __restrict__ off,
    const ushort* __restrict__ w_mf, ushort* __restrict__ y,
    float* __restrict__ psT) {
  __shared__ SMemU sm;

  int b = blockIdx.y;
  int p0 = blockIdx.x * TP;
  int bid = blockIdx.y * gridDim.x + blockIdx.x;
  int tid = threadIdx.x;
  const ushort* xb = xTh + (size_t)b * HW * 64;

  // ---- Phase A: bilinear metadata (288 tasks) ----
  for (int it = tid; it < KK * TP; it += 256) {
    int kk = it >> 5;
    int px = it & 31;
    int p = p0 + px;
    int ho = p / W, wo = p - ho * W;
    float dy = off[((size_t)b * OFFC + 2 * kk) * HW + p];
    float dx = off[((size_t)b * OFFC + 2 * kk + 1) * HW + p];
    float py = dy + (float)(ho - 1 + kk / 3);
    float pxx = dx + (float)(wo - 1 + kk % 3);
    float y0f = floorf(py), x0f = floorf(pxx);
    float wy1 = py - y0f, wx1 = pxx - x0f;
    int y0 = (int)y0f, x0 = (int)x0f;
    int y1 = y0 + 1, x1 = x0 + 1;
    float vy0 = (y0 >= 0 && y0 < H) ? 1.f : 0.f;
    float vy1 = (y1 >= 0 && y1 < H) ? 1.f : 0.f;
    float vx0 = (x0 >= 0 && x0 < W) ? 1.f : 0.f;
    float vx1 = (x1 >= 0 && x1 < W) ? 1.f : 0.f;
    int cy0 = min(max(y0, 0), H - 1), cy1 = min(max(y1, 0), H - 1);
    int cx0 = min(max(x0, 0), W - 1), cx1 = min(max(x1, 0), W - 1);
    float w00 = (1.f - wy1) * (1.f - wx1) * vy0 * vx0;
    float w01 = (1.f - wy1) * wx1 * vy0 * vx1;
    float w10 = wy1 * (1.f - wx1) * vy1 * vx0;
    float w11 = wy1 * wx1 * vy1 * vx1;
    sm.a.s_wh[kk][px] = make_uint4(pack_h2(w00, w00), pack_h2(w01, w01),
                                   pack_h2(w10, w10), pack_h2(w11, w11));
    sm.a.s_i[kk][px] = make_int4((cy0 * W + cx0) << 6, (cy0 * W + cx1) << 6,
                                 (cy1 * W + cx0) << 6, (cy1 * W + cx1) << 6);
  }
  __syncthreads();

  int wave = tid >> 6, lane = tid & 63;
  int row16 = lane & 15, quad = lane >> 4;
  int koff = quad * 8;
  int co_base = wave * 32;
  const ushort* wa0 = w_mf + (size_t)(co_base + row16) * KDIM + koff;
  const ushort* wa1 = w_mf + (size_t)(co_base + 16 + row16) * KDIM + koff;

  floatx4 acc00 = {0.f, 0.f, 0.f, 0.f}, acc01 = acc00, acc10 = acc00, acc11 = acc00;

  for (int h = 0; h < 2; ++h) {
    // ---- gather half h: 1152 tasks = 32px x 9kk x 4cig (8 ch each, packed f16) ----
#pragma unroll
    for (int r = 0; r < 5; ++r) {
      int it = tid + r * 256;
      if (it < 1152) {
        int px = it / 36;
        int rem = it - px * 36;
        int kk = rem >> 2;
        int cig = rem & 3;
        int cil0 = cig * 8;
        int cio = h * 32 + cil0;
        uint4 wh = sm.a.s_wh[kk][px];
        int4 iv = sm.a.s_i[kk][px];
        half2v w0 = u2h(wh.x), w1 = u2h(wh.y), w2 = u2h(wh.z), w3 = u2h(wh.w);
        uint4 c0 = *(const uint4*)(xb + iv.x + cio);
        uint4 c1 = *(const uint4*)(xb + iv.y + cio);
        uint4 c2 = *(const uint4*)(xb + iv.z + cio);
        uint4 c3 = *(const uint4*)(xb + iv.w + cio);
        uint4 res;
        res.x = h2u(w0 * u2h(c0.x) + w1 * u2h(c1.x) + w2 * u2h(c2.x) + w3 * u2h(c3.x));
        res.y = h2u(w0 * u2h(c0.y) + w1 * u2h(c1.y) + w2 * u2h(c2.y) + w3 * u2h(c3.y));
        res.z = h2u(w0 * u2h(c0.z) + w1 * u2h(c1.z) + w2 * u2h(c2.z) + w3 * u2h(c3.z));
        res.w = h2u(w0 * u2h(c0.w) + w1 * u2h(c1.w) + w2 * u2h(c2.w) + w3 * u2h(c3.w));
        *(uint4*)&sm.a.samp[px][kk * 32 + cil0] = res;
      }
    }
    __syncthreads();

    // ---- MFMA over this K-half: 9 ks steps x 4 MFMA ----
    const ushort* sb0 = &sm.a.samp[row16][koff];
    const ushort* sb1 = &sm.a.samp[16 + row16][koff];
    const ushort* a0 = wa0 + h * KHALF;
    const ushort* a1 = wa1 + h * KHALF;
#pragma unroll
    for (int ks = 0; ks < 9; ++ks) {
      half8 A0 = *(const half8*)(a0 + ks * 32);
      half8 A1 = *(const half8*)(a1 + ks * 32);
      half8 B0 = *(const half8*)(sb0 + ks * 32);
      half8 B1 = *(const half8*)(sb1 + ks * 32);
      acc00 = __builtin_amdgcn_mfma_f32_16x16x32_f16(A0, B0, acc00, 0, 0, 0);
      acc01 = __builtin_amdgcn_mfma_f32_16x16x32_f16(A0, B1, acc01, 0, 0, 0);
      acc10 = __builtin_amdgcn_mfma_f32_16x16x32_f16(A1, B0, acc10, 0, 0, 0);
      acc11 = __builtin_amdgcn_mfma_f32_16x16x32_f16(A1, B1, acc11, 0, 0, 0);
    }
    __syncthreads();   // h=0: samp reuse; h=1: before epilogue overlays SMem
  }

  // ---- epilogue 1: per-wave stats (fp32 accs) + LDS staging of y (f16) ----
#pragma unroll
  for (int reg = 0; reg < 4; ++reg) {
    int cA = co_base + quad * 4 + reg;
    int cB = cA + 16;
    sm.b.yst[cA][row16]      = f2h_bits(acc00[reg]);
    sm.b.yst[cA][16 + row16] = f2h_bits(acc01[reg]);
    sm.b.yst[cB][row16]      = f2h_bits(acc10[reg]);
    sm.b.yst[cB][16 + row16] = f2h_bits(acc11[reg]);
    float s0 = acc00[reg] + acc01[reg];
    float q0 = acc00[reg] * acc00[reg] + acc01[reg] * acc01[reg];
    float s1 = acc10[reg] + acc11[reg];
    float q1 = acc10[reg] * acc10[reg] + acc11[reg] * acc11[reg];
#pragma unroll
    for (int m = 1; m < 16; m <<= 1) {
      s0 += __shfl_xor(s0, m, 64);
      q0 += __shfl_xor(q0, m, 64);
      s1 += __shfl_xor(s1, m, 64);
      q1 += __shfl_xor(q1, m, 64);
    }
    if (row16 == 0) {
      sm.b.stat_s[cA] = s0;
      sm.b.stat_q[cA] = q0;
      sm.b.stat_s[cB] = s1;
      sm.b.stat_q[cB] = q1;
    }
  }
  __syncthreads();

  // ---- epilogue 2: cooperative full-line stores ----
  {
    int co = tid >> 1, seg = tid & 1;
    const ushort* row = &sm.b.yst[co][seg * 16];
    uint2 v0 = *(const uint2*)(row + 0);
    uint2 v1 = *(const uint2*)(row + 4);
    uint2 v2 = *(const uint2*)(row + 8);
    uint2 v3 = *(const uint2*)(row + 12);
    ushort* dst = y + (size_t)b * COUT * HW + (size_t)co * HW + p0 + seg * 16;
    *(uint4*)dst       = make_uint4(v0.x, v0.y, v1.x, v1.y);
    *(uint4*)(dst + 8) = make_uint4(v2.x, v2.y, v3.x, v3.y);
    float sv = (tid < 128) ? sm.b.stat_s[tid] : sm.b.stat_q[tid - 128];
    psT[(size_t)bid * 256 + tid] = sv;
  }
}

// ---------------- K4: reduce per-block partials -> stats[256], no atomics ----------------
__global__ __launch_bounds__(256) void k_reduce(const float* __restrict__ psT,
                                                float* __restrict__ stats) {
  int g = blockIdx.x;       // 0..63
  int tid = threadIdx.x;
  float4 a = make_float4(0.f, 0.f, 0.f, 0.f);
  for (int i = tid; i < NB; i += 256) {
    float4 v = *(const float4*)&psT[(size_t)i * 256 + g * 4];
    a.x += v.x; a.y += v.y; a.z += v.z; a.w += v.w;
  }
#pragma unroll
  for (int o = 32; o > 0; o >>= 1) {
    a.x += __shfl_down(a.x, o, 64);
    a.y += __shfl_down(a.y, o, 64);
    a.z += __shfl_down(a.z, o, 64);
    a.w += __shfl_down(a.w, o, 64);
  }
  __shared__ float4 ls[4];
  int lane = tid & 63, wid = tid >> 6;
  if (lane == 0) ls[wid] = a;
  __syncthreads();
  if (tid == 0) {
    float4 s;
    s.x = ls[0].x + ls[1].x + ls[2].x + ls[3].x;
    s.y = ls[0].y + ls[1].y + ls[2].y + ls[3].y;
    s.z = ls[0].z + ls[1].z + ls[2].z + ls[3].z;
    s.w = ls[0].w + ls[1].w + ls[2].w + ls[3].w;
    *(float4*)&stats[g * 4] = s;
  }
}

// ---------------- K5: finalize stats + normalize + ReLU (y f16 -> out fp32) ----------------
__global__ __launch_bounds__(256) void k_norm(const ushort* __restrict__ y,
                                              const float* __restrict__ stats,
                                              const float* __restrict__ gamma,
                                              const float* __restrict__ beta,
                                              float* __restrict__ out) {
  int i8 = blockIdx.x * 256 + threadIdx.x;
  const int total8 = BATCH * COUT * HW / 8;
  if (i8 >= total8) return;
  size_t i = (size_t)i8 * 8;
  int c = (int)((i / HW) & (COUT - 1));
  const float N = (float)(BATCH * HW);
  float m = stats[c] / N;
  float var = stats[COUT + c] / N - m * m;
  float r = rsqrtf(var + EPS);
  float g = gamma[c], bt = beta[c];
  float a = r * g;
  float base = bt - m * a;
  uint4 u = *(const uint4*)&y[i];
  float4 o0, o1;
  half2v h0 = u2h(u.x), h1 = u2h(u.y), h2 = u2h(u.z), h3 = u2h(u.w);
  o0.x = fmaxf(0.f, fmaf((float)h0[0], a, base));
  o0.y = fmaxf(0.f, fmaf((float)h0[1], a, base));
  o0.z = fmaxf(0.f, fmaf((float)h1[0], a, base));
  o0.w = fmaxf(0.f, fmaf((float)h1[1], a, base));
  o1.x = fmaxf(0.f, fmaf((float)h2[0], a, base));
  o1.y = fmaxf(0.f, fmaf((float)h2[1], a, base));
  o1.z = fmaxf(0.f, fmaf((float)h3[0], a, base));
  o1.w = fmaxf(0.f, fmaf((float)h3[1], a, base));
  *(float4*)&out[i]     = o0;
  *(float4*)&out[i + 4] = o1;
}

extern "C" void kernel_launch(void* const* d_in, const int* in_sizes, int n_in,
                              void* d_out, int out_size, void* d_ws, size_t ws_size,
                              hipStream_t stream) {
  const float* x     = (const float*)d_in[0];
  const float* w_off = (const float*)d_in[1];
  const float* b_off = (const float*)d_in[2];
  const float* w_dcn = (const float*)d_in[3];
  // d_in[4] = b_dcn: cancels exactly through batch-norm
  const float* gamma = (const float*)d_in[5];
  const float* beta  = (const float*)d_in[6];
  float* out = (float*)d_out;

  float* ws = (float*)d_ws;
  float*  off_buf = ws;                               //  1,806,336 floats
  float*  psT     = off_buf + 1806336;                //    802,816 floats
  float*  stats   = psT + 802816;                     //        256
  ushort* xTh     = (ushort*)(stats + 256);           //  6,422,528 ushorts
  ushort* w_mf    = xTh + 6422528;                    //     73,728
  ushort* w_offT  = w_mf + 73728;                     //     18,432
  ushort* y_h     = w_offT + 18432;                   // 12,845,056 ushorts
  // total ~49 MB

  k_transpose_prep<<<1928, 256, 0, stream>>>(x, w_off, w_dcn, xTh, w_offT, w_mf);
  k_offset_conv<<<dim3(HW / 64, BATCH), 256, 0, stream>>>(xTh, w_offT, b_off, off_buf);
  k_deform<<<dim3(HW / TP, BATCH), 256, 0, stream>>>(xTh, off_buf, w_mf, y_h, psT);
  k_reduce<<<64, 256, 0, stream>>>(psT, stats);
  k_norm<<<(BATCH * COUT * HW / 8 + 255) / 256, 256, 0, stream>>>(y_h, stats, gamma, beta, out);
}